// Round 4
// baseline (286.060 us; speedup 1.0000x reference)
//
#include <hip/hip_runtime.h>
#include <hip/hip_bf16.h>
#include <stdint.h>

#define DEV __device__ __forceinline__

typedef __attribute__((ext_vector_type(8))) short short8;
typedef __attribute__((ext_vector_type(8))) _Float16 half8;
typedef __attribute__((ext_vector_type(2))) __fp16 fp16x2;
typedef __attribute__((ext_vector_type(4))) float floatx4;
typedef __attribute__((ext_vector_type(16))) float floatx16;

DEV unsigned short f2bf(float f) {
  union { float f; uint32_t u; } v; v.f = f;
  uint32_t u = v.u;
  u += 0x7fffu + ((u >> 16) & 1u);   // RNE
  return (unsigned short)(u >> 16);
}
DEV unsigned short f2h(float f) {
  union { _Float16 h; unsigned short u; } c; c.h = (_Float16)f; return c.u;
}
DEV void async_cp16(const unsigned short* g, unsigned short* l) {
  __builtin_amdgcn_global_load_lds(
      (const __attribute__((address_space(1))) uint32_t*)g,
      (__attribute__((address_space(3))) uint32_t*)l, 16, 0, 0);
}

// ---------------------------------------------------------------------------
// cvt_x: fp32 -> bf16, coalesced. n multiple of 1024.
// ---------------------------------------------------------------------------
__global__ __launch_bounds__(256)
void cvt_x_kernel(const float* __restrict__ x, unsigned short* __restrict__ xb) {
  const size_t i = ((size_t)blockIdx.x * 256 + threadIdx.x) * 4;
  const float4 f = *(const float4*)(x + i);
  ushort4 w;
  w.x = f2bf(f.x); w.y = f2bf(f.y); w.z = f2bf(f.z); w.w = f2bf(f.w);
  *(ushort4*)(xb + i) = w;
}

// ---------------------------------------------------------------------------
// transpose_w: W[K][N] fp32 -> Wt[N][K] bf16. 64x64 LDS tiles.
// ---------------------------------------------------------------------------
__global__ __launch_bounds__(256)
void transpose_w_kernel(const float* __restrict__ W, unsigned short* __restrict__ Wt,
                        int K, int N) {
  __shared__ float tile[64][65];
  const int k0 = blockIdx.y * 64, n0 = blockIdx.x * 64;
  const int tr = threadIdx.x >> 4;
  const int tc = (threadIdx.x & 15) * 4;
#pragma unroll
  for (int it = 0; it < 4; ++it) {
    const int k = tr + it * 16;
    const float4 f = *(const float4*)(W + (size_t)(k0 + k) * N + n0 + tc);
    tile[k][tc + 0] = f.x; tile[k][tc + 1] = f.y;
    tile[k][tc + 2] = f.z; tile[k][tc + 3] = f.w;
  }
  __syncthreads();
#pragma unroll
  for (int it = 0; it < 4; ++it) {
    const int n = tr + it * 16;
    ushort4 w;
    w.x = f2bf(tile[tc + 0][n]); w.y = f2bf(tile[tc + 1][n]);
    w.z = f2bf(tile[tc + 2][n]); w.w = f2bf(tile[tc + 3][n]);
    *(ushort4*)(Wt + (size_t)(n0 + n) * K + k0 + tc) = w;
  }
}

// ---------------------------------------------------------------------------
// 256x256 8-phase bf16 GEMM. C = A[M,K] * Bt[N,K]^T + bias.
// 512 thr = 8 waves (2M x 4N), per-wave C 128x64, BK=64, K=1024 (16 tiles).
// LDS 128KB: L[2][ A[256][64] | B[256][64] ], T2 row-XOR swizzle via
// pre-swizzled global source (linear DMA dest) + XOR'd ds_read.
//
// Region-lifetime-safe stage schedule (buf P = t&1):
//   ph1 (mh0,ks0,RB): stage A0(t+1)->P^1   [P^1 A-regions free since t-1 ph4 bar]
//   ph2 (mh1,ks0   ): stage A1(t+1)->P^1
//   ph3 (mh0,ks1,RB): no stage
//   ph4 (mh1,ks1   ): stage B0+B1(t+2)->P  [P B-regions free since t ph3 bar]
//                     then vmcnt(4): all but B01(t+2) landed => t+1 resident.
// NOTE: no hand lgkmcnt(0) before the MFMAs — the ds_reads are compiler-
// visible, so hipcc inserts INCREMENTAL lgkmcnt(N) waits per MFMA, letting
// early MFMAs overlap the tail of the LDS read drain (a blanket lgkmcnt(0)
// serialized drain vs compute and pinned MfmaUtil at ~20%).
// ---------------------------------------------------------------------------
#define BAR asm volatile("s_barrier" ::: "memory")
#define VMW(N) asm volatile("s_waitcnt vmcnt(" #N ")" ::: "memory")
#define NOW (void)0
#define NOSTG (void)0

template <int EPI>
__global__ __launch_bounds__(512, 2)
void gemm256_kernel(const unsigned short* __restrict__ A,
                    const unsigned short* __restrict__ Bt,
                    const float* __restrict__ bias, int M, int N, int K,
                    int nbx,
                    unsigned short* __restrict__ qws,
                    unsigned short* __restrict__ kws,
                    unsigned short* __restrict__ vws,
                    float* __restrict__ out) {
  (void)M;
  __shared__ __align__(16) unsigned short L[2][32768];  // [buf][A:0..16383|B:16384..]
  const int tid = threadIdx.x;
  const int wid = tid >> 6, lane = tid & 63;
  const int quad = lane >> 4, l16 = lane & 15;
  const int wm = wid >> 2, wn = wid & 3;

  // T1: XCD-aware swizzle (gridDim.x % 8 == 0 at both call sites -> bijective).
  const int nwg = (int)gridDim.x;
  const int bid = (int)blockIdx.x;
  const int swz = (bid & 7) * (nwg >> 3) + (bid >> 3);
  const int bx = swz % nbx, by = swz / nbx;
  const int rowA0 = by * 256, colB0 = bx * 256;

  // Staging: thread tid covers LDS shorts [tid*8, tid*8+8) of a 64-row half
  // tile region (row = tid>>3, slot = tid&7). Pre-swizzled source: data at
  // slot s of row r holds logical k = (s ^ (r&7))*8.
  const int srow = tid >> 3;                              // 0..63
  const int ksrc = (((tid & 7) ^ (srow & 7)) << 3);       // shorts
  const unsigned short* pA00 = A + (size_t)(rowA0 + 0   + srow) * K + ksrc;
  const unsigned short* pA01 = A + (size_t)(rowA0 + 64  + srow) * K + ksrc;
  const unsigned short* pA10 = A + (size_t)(rowA0 + 128 + srow) * K + ksrc;
  const unsigned short* pA11 = A + (size_t)(rowA0 + 192 + srow) * K + ksrc;
  const unsigned short* pB00 = Bt + (size_t)(colB0 + 0   + srow) * K + ksrc;
  const unsigned short* pB01 = Bt + (size_t)(colB0 + 64  + srow) * K + ksrc;
  const unsigned short* pB10 = Bt + (size_t)(colB0 + 128 + srow) * K + ksrc;
  const unsigned short* pB11 = Bt + (size_t)(colB0 + 192 + srow) * K + ksrc;

#define STG_A0(P, T) do { async_cp16(pA00 + (T)*64, &L[P][0     + wid*512]); \
                          async_cp16(pA01 + (T)*64, &L[P][4096  + wid*512]); } while (0)
#define STG_A1(P, T) do { async_cp16(pA10 + (T)*64, &L[P][8192  + wid*512]); \
                          async_cp16(pA11 + (T)*64, &L[P][12288 + wid*512]); } while (0)
#define STG_B0(P, T) do { async_cp16(pB00 + (T)*64, &L[P][16384 + wid*512]); \
                          async_cp16(pB01 + (T)*64, &L[P][20480 + wid*512]); } while (0)
#define STG_B1(P, T) do { async_cp16(pB10 + (T)*64, &L[P][24576 + wid*512]); \
                          async_cp16(pB11 + (T)*64, &L[P][28672 + wid*512]); } while (0)
#define STG_B01(P, T) do { STG_B0(P, T); STG_B1(P, T); } while (0)

  floatx4 acc[8][4];
#pragma unroll
  for (int i = 0; i < 8; ++i)
#pragma unroll
    for (int j = 0; j < 4; ++j) acc[i][j] = (floatx4){0.f, 0.f, 0.f, 0.f};
  short8 bfrag[4];

  // Prologue: tile0 (8 loads) + B01 of tile1 (4 loads); vmcnt(4) leaves only
  // B01(t1) in flight => tile0 fully resident. (Steady-state invariant.)
  STG_A0(0, 0); STG_A1(0, 0); STG_B0(0, 0); STG_B1(0, 0);
  STG_B01(1, 1);
  VMW(4);
  BAR;

#define PHASE(PAR, QM, KS, RB, STG, W)                                        \
  {                                                                           \
    short8 a_[4];                                                             \
    _Pragma("unroll") for (int m_ = 0; m_ < 4; ++m_) {                        \
      const int row_ = wm * 128 + ((QM)*4 + m_) * 16 + l16;                   \
      a_[m_] = *(const short8*)&L[PAR][row_ * 64 +                            \
                 ((((KS)*32) + quad * 8) ^ ((row_ & 7) << 3))];               \
    }                                                                         \
    if (RB) {                                                                 \
      _Pragma("unroll") for (int n_ = 0; n_ < 4; ++n_) {                      \
        const int row_ = wn * 64 + n_ * 16 + l16;                             \
        bfrag[n_] = *(const short8*)&L[PAR][16384 + row_ * 64 +               \
                 ((((KS)*32) + quad * 8) ^ ((row_ & 7) << 3))];               \
      }                                                                       \
    }                                                                         \
    STG;                                                                      \
    BAR;                                                                      \
    __builtin_amdgcn_s_setprio(1);                                            \
    _Pragma("unroll") for (int m_ = 0; m_ < 4; ++m_)                          \
      _Pragma("unroll") for (int n_ = 0; n_ < 4; ++n_)                        \
        acc[(QM)*4 + m_][n_] = __builtin_amdgcn_mfma_f32_16x16x32_bf16(       \
            a_[m_], bfrag[n_], acc[(QM)*4 + m_][n_], 0, 0, 0);                \
    __builtin_amdgcn_s_setprio(0);                                            \
    W;                                                                        \
    BAR;                                                                      \
  }

#define KTILE(PAR, S1, S2, S4, W4) \
  PHASE(PAR, 0, 0, 1, S1, NOW)     \
  PHASE(PAR, 1, 0, 0, S2, NOW)     \
  PHASE(PAR, 0, 1, 1, NOSTG, NOW)  \
  PHASE(PAR, 1, 1, 0, S4, W4)

  // Steady: tiles 0..13 (K=1024 -> 16 tiles at both call sites).
  for (int t0 = 0; t0 < 14; t0 += 2) {
    KTILE(0, STG_A0(1, t0 + 1), STG_A1(1, t0 + 1), STG_B01(0, t0 + 2), VMW(4))
    KTILE(1, STG_A0(0, t0 + 2), STG_A1(0, t0 + 2), STG_B01(1, t0 + 3), VMW(4))
  }
  // Tile 14: stage A of tile 15, drain everything; tile 15: pure compute.
  KTILE(0, STG_A0(1, 15), STG_A1(1, 15), NOSTG, VMW(0))
  KTILE(1, NOSTG, NOSTG, NOSTG, NOW)

#undef KTILE
#undef PHASE
#undef STG_A0
#undef STG_A1
#undef STG_B0
#undef STG_B1
#undef STG_B01

  // Epilogue. C/D: row = quad*4 + r, col = l16 (dtype-independent).
#pragma unroll
  for (int mi = 0; mi < 8; ++mi) {
#pragma unroll
    for (int ni = 0; ni < 4; ++ni) {
      const int row0 = rowA0 + wm * 128 + mi * 16 + quad * 4;
      const int col = colB0 + wn * 64 + ni * 16 + l16;
      const float bv = bias[col];
#pragma unroll
      for (int r = 0; r < 4; ++r) {
        const float v = acc[mi][ni][r] + bv;
        const int R = row0 + r;
        if constexpr (EPI == 0) {
          const int b = R >> 11, t = R & 2047;
          const int which = col >> 10, c = col & 1023;
          const int h = c >> 6, dd = c & 63;
          const size_t bh = (size_t)(b * 16 + h);
          if (which == 0)
            qws[(bh * 2048 + t) * 64 + dd] = f2bf(v * 0.125f);  // Q, scale folded
          else if (which == 1)
            kws[(bh * 2048 + t) * 64 + dd] = f2bf(v);           // K [bh][t][d]
          else
            vws[(bh * 64 + dd) * 2048 + t] = f2h(v);            // V^T f16 [bh][d][t]
        } else {
          out[(size_t)R * N + col] = v;
        }
      }
    }
  }
}

// ---------------------------------------------------------------------------
// MFMA flash attention (unchanged). Grid (64 bh, 16 qtiles), block 256.
// ---------------------------------------------------------------------------
__global__ __launch_bounds__(256, 2)
void attn_mfma_kernel(const unsigned short* __restrict__ qws,
                      const unsigned short* __restrict__ kws,
                      const unsigned short* __restrict__ vws,
                      unsigned short* __restrict__ yws) {
  constexpr int T = 2048, D = 64;
  __shared__ __align__(16) unsigned short Ks[128 * 72];
  __shared__ __align__(16) unsigned short Vs[64 * 136];
  const int tid = threadIdx.x;
  const int wid = tid >> 6, lane = tid & 63;
  const int hf = lane >> 5, l32 = lane & 31;
  const int bh = blockIdx.x;
  const int qt = 15 - (int)blockIdx.y;
  const int qbase = qt * 128;
  const unsigned short* Qp = qws + (size_t)bh * T * D;
  const unsigned short* Kp = kws + (size_t)bh * T * D;
  const unsigned short* Vp = vws + (size_t)bh * D * T;

  const int q = qbase + wid * 32 + l32;
  short8 qf[4];
#pragma unroll
  for (int s = 0; s < 4; ++s)
    qf[s] = *(const short8*)(Qp + (size_t)q * D + s * 16 + hf * 8);

  floatx16 Oacc[2];
#pragma unroll
  for (int mt2 = 0; mt2 < 2; ++mt2)
#pragma unroll
    for (int i = 0; i < 16; ++i) Oacc[mt2][i] = 0.f;
  float mrun = -1e30f, lrun = 0.f;

  for (int kt = 0; kt <= qt; ++kt) {
    const int kb = kt * 128;
    __syncthreads();
#pragma unroll
    for (int it = 0; it < 4; ++it) {
      const int e = it * 256 + tid;
      {
        const int row = e >> 3, c = (e & 7) * 8;
        *(short8*)&Ks[row * 72 + c] =
            *(const short8*)(Kp + (size_t)(kb + row) * D + c);
      }
      {
        const int row = e >> 4, c = (e & 15) * 8;
        *(short8*)&Vs[row * 136 + c] =
            *(const short8*)(Vp + (size_t)row * T + kb + c);
      }
    }
    __syncthreads();

    const bool diag = (kt == qt);
    const int mtmax = diag ? (wid + 1) : 4;

    floatx16 S[4];
#pragma unroll
    for (int mt = 0; mt < 4; ++mt)
      if (mt < mtmax)
#pragma unroll
        for (int i = 0; i < 16; ++i) S[mt][i] = 0.f;

#pragma unroll
    for (int s = 0; s < 4; ++s) {
#pragma unroll
      for (int mt = 0; mt < 4; ++mt)
        if (mt < mtmax) {
          const short8 kf =
              *(const short8*)&Ks[(mt * 32 + l32) * 72 + s * 16 + hf * 8];
          S[mt] = __builtin_amdgcn_mfma_f32_32x32x16_bf16(kf, qf[s], S[mt], 0, 0, 0);
        }
    }

    if (diag) {
#pragma unroll
      for (int mt = 0; mt < 4; ++mt)
        if (mt == wid) {
#pragma unroll
          for (int r = 0; r < 16; ++r) {
            const int intra = (r & 3) + 8 * (r >> 2) + 4 * hf;
            if (intra > l32) S[mt][r] = -1e30f;
          }
        }
    }

    float tmax = -1e30f;
#pragma unroll
    for (int mt = 0; mt < 4; ++mt)
      if (mt < mtmax)
#pragma unroll
        for (int r = 0; r < 16; ++r) tmax = fmaxf(tmax, S[mt][r]);
    tmax = fmaxf(tmax, __shfl_xor(tmax, 32, 64));
    const float mn = fmaxf(mrun, tmax);
    const float alpha = __expf(mrun - mn);
    mrun = mn;

    float tsum = 0.f;
    uint32_t pk[4][8];
#pragma unroll
    for (int mt = 0; mt < 4; ++mt)
      if (mt < mtmax)
#pragma unroll
        for (int t = 0; t < 8; ++t) {
          const float pa = __expf(S[mt][2 * t] - mn);
          const float pb = __expf(S[mt][2 * t + 1] - mn);
          tsum += pa + pb;
          union { fp16x2 h; uint32_t u; } cv;
          cv.h = __builtin_amdgcn_cvt_pkrtz(pa, pb);
          pk[mt][t] = cv.u;
        }
    tsum += __shfl_xor(tsum, 32, 64);
    lrun = lrun * alpha + tsum;
#pragma unroll
    for (int mt2 = 0; mt2 < 2; ++mt2)
#pragma unroll
      for (int i = 0; i < 16; ++i) Oacc[mt2][i] *= alpha;

    const int smax = 2 * mtmax;
#pragma unroll
    for (int s = 0; s < 8; ++s)
      if (s < smax) {
        const int mt = s >> 1;
        const int bo = 4 * (s & 1);
        const uint32_t own0 = hf ? pk[mt][bo + 2] : pk[mt][bo];
        const uint32_t own1 = hf ? pk[mt][bo + 3] : pk[mt][bo + 1];
        const uint32_t sendA = hf ? pk[mt][bo] : pk[mt][bo + 2];
        const uint32_t sendB = hf ? pk[mt][bo + 1] : pk[mt][bo + 3];
        const uint32_t recvA = (uint32_t)__shfl_xor((int)sendA, 32, 64);
        const uint32_t recvB = (uint32_t)__shfl_xor((int)sendB, 32, 64);
        union { uint32_t u[4]; half8 h; } bb;
        bb.u[0] = hf ? recvA : own0;
        bb.u[1] = hf ? recvB : own1;
        bb.u[2] = hf ? own0 : recvA;
        bb.u[3] = hf ? own1 : recvB;
#pragma unroll
        for (int mt2 = 0; mt2 < 2; ++mt2) {
          const half8 vf =
              *(const half8*)&Vs[(mt2 * 32 + l32) * 136 + s * 16 + hf * 8];
          Oacc[mt2] = __builtin_amdgcn_mfma_f32_32x32x16_f16(vf, bb.h, Oacc[mt2], 0, 0, 0);
        }
      }
  }

  const float invl = 1.0f / lrun;
  const int b_ = bh >> 4, h_ = bh & 15;
  unsigned short* yrow = yws + ((size_t)(b_ * 2048 + q)) * 1024 + h_ * 64;
#pragma unroll
  for (int mt2 = 0; mt2 < 2; ++mt2)
#pragma unroll
    for (int t = 0; t < 8; ++t) {
      const int d0 = mt2 * 32 + 2 * (t & 1) + 8 * (t >> 1) + 4 * hf;
      const uint32_t ua = f2bf(Oacc[mt2][2 * t] * invl);
      const uint32_t ub = f2bf(Oacc[mt2][2 * t + 1] * invl);
      *(uint32_t*)&yrow[d0] = ua | (ub << 16);
    }
}

// ---------------------------------------------------------------------------
extern "C" void kernel_launch(void* const* d_in, const int* in_sizes, int n_in,
                              void* d_out, int out_size, void* d_ws, size_t ws_size,
                              hipStream_t stream) {
  (void)in_sizes; (void)n_in; (void)out_size;
  const float* x = (const float*)d_in[0];
  const float* attn_w = (const float*)d_in[1];
  const float* attn_b = (const float*)d_in[2];
  const float* proj_w = (const float*)d_in[3];
  const float* proj_b = (const float*)d_in[4];
  float* out = (float*)d_out;

  const size_t NQ = 8388608;  // 4*16*2048*64 == 8192*1024
  unsigned short* qws = (unsigned short*)d_ws;
  unsigned short* kws = qws + NQ;
  unsigned short* vws = kws + NQ;
  unsigned short* yws = vws + NQ;
  unsigned short* xb  = yws + NQ;
  unsigned short* wta = xb + NQ;               // 3072*1024
  unsigned short* wtp = wta + 3072 * 1024;     // 1024*1024
  if (ws_size < (5 * NQ + 4 * 1024 * 1024) * sizeof(unsigned short)) return;

  cvt_x_kernel<<<dim3(8192), dim3(256), 0, stream>>>(x, xb);
  transpose_w_kernel<<<dim3(48, 16), dim3(256), 0, stream>>>(attn_w, wta, 1024, 3072);
  transpose_w_kernel<<<dim3(16, 16), dim3(256), 0, stream>>>(proj_w, wtp, 1024, 1024);

  // QKV: M=8192, N=3072, K=1024 -> 32x12 = 384 blocks (384 % 8 == 0).
  gemm256_kernel<0><<<dim3(384), dim3(512), 0, stream>>>(
      xb, wta, attn_b, 8192, 3072, 1024, 12, qws, kws, vws, nullptr);
  attn_mfma_kernel<<<dim3(64, 16), dim3(256), 0, stream>>>(qws, kws, vws, yws);
  // Proj: M=8192, N=1024, K=1024 -> 32x4 = 128 blocks (128 % 8 == 0).
  gemm256_kernel<1><<<dim3(128), dim3(512), 0, stream>>>(
      yws, wtp, proj_b, 8192, 1024, 1024, 4, nullptr, nullptr, nullptr, out);
}

// Round 5
// 273.537 us; speedup vs baseline: 1.0458x; 1.0458x over previous
//
#include <hip/hip_runtime.h>
#include <hip/hip_bf16.h>
#include <stdint.h>

#define DEV __device__ __forceinline__

typedef __attribute__((ext_vector_type(8))) short short8;
typedef __attribute__((ext_vector_type(8))) _Float16 half8;
typedef __attribute__((ext_vector_type(2))) __fp16 fp16x2;
typedef __attribute__((ext_vector_type(4))) float floatx4;
typedef __attribute__((ext_vector_type(16))) float floatx16;

DEV unsigned short f2bf(float f) {
  union { float f; uint32_t u; } v; v.f = f;
  uint32_t u = v.u;
  u += 0x7fffu + ((u >> 16) & 1u);   // RNE
  return (unsigned short)(u >> 16);
}
DEV unsigned short f2h(float f) {
  union { _Float16 h; unsigned short u; } c; c.h = (_Float16)f; return c.u;
}
DEV void async_cp16(const unsigned short* g, unsigned short* l) {
  __builtin_amdgcn_global_load_lds(
      (const __attribute__((address_space(1))) uint32_t*)g,
      (__attribute__((address_space(3))) uint32_t*)l, 16, 0, 0);
}

// ---------------------------------------------------------------------------
// cvt_x: fp32 -> bf16, coalesced. n multiple of 1024.
// ---------------------------------------------------------------------------
__global__ __launch_bounds__(256)
void cvt_x_kernel(const float* __restrict__ x, unsigned short* __restrict__ xb) {
  const size_t i = ((size_t)blockIdx.x * 256 + threadIdx.x) * 4;
  const float4 f = *(const float4*)(x + i);
  ushort4 w;
  w.x = f2bf(f.x); w.y = f2bf(f.y); w.z = f2bf(f.z); w.w = f2bf(f.w);
  *(ushort4*)(xb + i) = w;
}

// ---------------------------------------------------------------------------
// transpose_w: W[K][N] fp32 -> Wt[N][K] bf16. 64x64 LDS tiles.
// ---------------------------------------------------------------------------
__global__ __launch_bounds__(256)
void transpose_w_kernel(const float* __restrict__ W, unsigned short* __restrict__ Wt,
                        int K, int N) {
  __shared__ float tile[64][65];
  const int k0 = blockIdx.y * 64, n0 = blockIdx.x * 64;
  const int tr = threadIdx.x >> 4;
  const int tc = (threadIdx.x & 15) * 4;
#pragma unroll
  for (int it = 0; it < 4; ++it) {
    const int k = tr + it * 16;
    const float4 f = *(const float4*)(W + (size_t)(k0 + k) * N + n0 + tc);
    tile[k][tc + 0] = f.x; tile[k][tc + 1] = f.y;
    tile[k][tc + 2] = f.z; tile[k][tc + 3] = f.w;
  }
  __syncthreads();
#pragma unroll
  for (int it = 0; it < 4; ++it) {
    const int n = tr + it * 16;
    ushort4 w;
    w.x = f2bf(tile[tc + 0][n]); w.y = f2bf(tile[tc + 1][n]);
    w.z = f2bf(tile[tc + 2][n]); w.w = f2bf(tile[tc + 3][n]);
    *(ushort4*)(Wt + (size_t)(n0 + n) * K + k0 + tc) = w;
  }
}

// ---------------------------------------------------------------------------
// 256xBN 8-phase bf16 GEMM. C = A[M,K] * Bt[N,K]^T + bias.  BN in {256,128}.
// 512 thr = 8 waves (2M x 4N), per-wave C 128 x BN/4, BK=64, 16 K-tiles.
// LDS: L[2][ A[256][64] | B[BN][64] ] (128KB / 96KB). T2 row-XOR swizzle via
// pre-swizzled global source (linear DMA dest) + XOR'd ds_read.
//
// Region-lifetime-safe stage schedule (buf P = t&1), NF = BN/64 B-regions:
//   ph1: stage A0(t+1)->P^1   ph2: stage A1(t+1)->P^1   ph3: none
//   ph4: stage B(t+2)->P [B of P free since ph3 bar], then vmcnt(NF):
//        all but B(t+2) landed => tile t+1 fully resident.
// LGK0 after the barrier (r3-proven): explicit drain beats the compiler's
// conservative WAR handling between pending ds_reads and the DMA stage
// (removing it moved the wait BEFORE the stage issue: 100 -> 138 us, r4).
// ---------------------------------------------------------------------------
#define BAR asm volatile("s_barrier" ::: "memory")
#define LGK0 asm volatile("s_waitcnt lgkmcnt(0)" ::: "memory")
#define VMW(N) asm volatile("s_waitcnt vmcnt(" #N ")" ::: "memory")
#define NOW (void)0
#define NOSTG (void)0

template <int EPI, int BN>
__global__ __launch_bounds__(512, 2)
void gemm256_kernel(const unsigned short* __restrict__ A,
                    const unsigned short* __restrict__ Bt,
                    const float* __restrict__ bias, int M, int N, int K,
                    int nbx,
                    unsigned short* __restrict__ qws,
                    unsigned short* __restrict__ kws,
                    unsigned short* __restrict__ vws,
                    float* __restrict__ out) {
  (void)M;
  constexpr int NF = BN / 64;  // B 64-row regions == per-wave n-frags
  __shared__ __align__(16) unsigned short L[2][16384 + NF * 4096];
  const int tid = threadIdx.x;
  const int wid = tid >> 6, lane = tid & 63;
  const int quad = lane >> 4, l16 = lane & 15;
  const int wm = wid >> 2, wn = wid & 3;

  // T1: XCD-aware swizzle (gridDim.x % 8 == 0 at both call sites -> bijective).
  const int nwg = (int)gridDim.x;
  const int bid = (int)blockIdx.x;
  const int swz = (bid & 7) * (nwg >> 3) + (bid >> 3);
  const int bx = swz % nbx, by = swz / nbx;
  const int rowA0 = by * 256, colB0 = bx * BN;

  // Staging: thread tid covers LDS shorts [tid*8, tid*8+8) of a 64-row
  // region (row = tid>>3, slot = tid&7). Pre-swizzled source: data at
  // slot s of row r holds logical k = (s ^ (r&7))*8.
  const int srow = tid >> 3;                              // 0..63
  const int ksrc = (((tid & 7) ^ (srow & 7)) << 3);       // shorts
  const unsigned short* pA00 = A + (size_t)(rowA0 + 0   + srow) * K + ksrc;
  const unsigned short* pA01 = A + (size_t)(rowA0 + 64  + srow) * K + ksrc;
  const unsigned short* pA10 = A + (size_t)(rowA0 + 128 + srow) * K + ksrc;
  const unsigned short* pA11 = A + (size_t)(rowA0 + 192 + srow) * K + ksrc;
  const unsigned short* pB00 = Bt + (size_t)(colB0 + 0   + srow) * K + ksrc;
  const unsigned short* pB01 = Bt + (size_t)(colB0 + 64  + srow) * K + ksrc;
  const unsigned short* pB10 =
      (BN == 256) ? Bt + (size_t)(colB0 + 128 + srow) * K + ksrc : pB00;
  const unsigned short* pB11 =
      (BN == 256) ? Bt + (size_t)(colB0 + 192 + srow) * K + ksrc : pB00;

#define STG_A0(P, T) do { async_cp16(pA00 + (T)*64, &L[P][0     + wid*512]); \
                          async_cp16(pA01 + (T)*64, &L[P][4096  + wid*512]); } while (0)
#define STG_A1(P, T) do { async_cp16(pA10 + (T)*64, &L[P][8192  + wid*512]); \
                          async_cp16(pA11 + (T)*64, &L[P][12288 + wid*512]); } while (0)
#define STG_B(P, T) do { \
    async_cp16(pB00 + (T)*64, &L[P][16384 + wid*512]); \
    async_cp16(pB01 + (T)*64, &L[P][20480 + wid*512]); \
    if constexpr (BN == 256) { \
      async_cp16(pB10 + (T)*64, &L[P][24576 + wid*512]); \
      async_cp16(pB11 + (T)*64, &L[P][28672 + wid*512]); } } while (0)
#define VMW_STEADY do { if constexpr (BN == 256) { VMW(4); } else { VMW(2); } } while (0)

  floatx4 acc[8][NF];
#pragma unroll
  for (int i = 0; i < 8; ++i)
#pragma unroll
    for (int j = 0; j < NF; ++j) acc[i][j] = (floatx4){0.f, 0.f, 0.f, 0.f};
  short8 bfrag[NF];

  // Prologue: tile0 (4+NF loads) + B of tile1 (NF); vmcnt(NF) leaves only
  // B(t1) in flight => tile0 fully resident. (Steady-state invariant.)
  STG_A0(0, 0); STG_A1(0, 0); STG_B(0, 0);
  STG_B(1, 1);
  VMW_STEADY;
  BAR;

#define PHASE(PAR, QM, KS, RB, STG, W)                                        \
  {                                                                           \
    short8 a_[4];                                                             \
    _Pragma("unroll") for (int m_ = 0; m_ < 4; ++m_) {                        \
      const int row_ = wm * 128 + ((QM)*4 + m_) * 16 + l16;                   \
      a_[m_] = *(const short8*)&L[PAR][row_ * 64 +                            \
                 ((((KS)*32) + quad * 8) ^ ((row_ & 7) << 3))];               \
    }                                                                         \
    if (RB) {                                                                 \
      _Pragma("unroll") for (int n_ = 0; n_ < NF; ++n_) {                     \
        const int row_ = wn * (BN / 4) + n_ * 16 + l16;                       \
        bfrag[n_] = *(const short8*)&L[PAR][16384 + row_ * 64 +               \
                 ((((KS)*32) + quad * 8) ^ ((row_ & 7) << 3))];               \
      }                                                                       \
    }                                                                         \
    STG;                                                                      \
    BAR;                                                                      \
    LGK0;                                                                     \
    __builtin_amdgcn_s_setprio(1);                                            \
    _Pragma("unroll") for (int m_ = 0; m_ < 4; ++m_)                          \
      _Pragma("unroll") for (int n_ = 0; n_ < NF; ++n_)                       \
        acc[(QM)*4 + m_][n_] = __builtin_amdgcn_mfma_f32_16x16x32_bf16(       \
            a_[m_], bfrag[n_], acc[(QM)*4 + m_][n_], 0, 0, 0);                \
    __builtin_amdgcn_s_setprio(0);                                            \
    W;                                                                        \
    BAR;                                                                      \
  }

#define KTILE(PAR, S1, S2, S4, W4) \
  PHASE(PAR, 0, 0, 1, S1, NOW)     \
  PHASE(PAR, 1, 0, 0, S2, NOW)     \
  PHASE(PAR, 0, 1, 1, NOSTG, NOW)  \
  PHASE(PAR, 1, 1, 0, S4, W4)

  // Steady: tiles 0..13 (K=1024 -> 16 tiles at both call sites).
  for (int t0 = 0; t0 < 14; t0 += 2) {
    KTILE(0, STG_A0(1, t0 + 1), STG_A1(1, t0 + 1), STG_B(0, t0 + 2), VMW_STEADY)
    KTILE(1, STG_A0(0, t0 + 2), STG_A1(0, t0 + 2), STG_B(1, t0 + 3), VMW_STEADY)
  }
  // Tile 14: stage A of tile 15, drain everything; tile 15: pure compute.
  KTILE(0, STG_A0(1, 15), STG_A1(1, 15), NOSTG, VMW(0))
  KTILE(1, NOSTG, NOSTG, NOSTG, NOW)

#undef KTILE
#undef PHASE
#undef STG_A0
#undef STG_A1
#undef STG_B
#undef VMW_STEADY

  // Epilogue. C/D: row = quad*4 + r, col = l16 (dtype-independent).
#pragma unroll
  for (int mi = 0; mi < 8; ++mi) {
#pragma unroll
    for (int ni = 0; ni < NF; ++ni) {
      const int row0 = rowA0 + wm * 128 + mi * 16 + quad * 4;
      const int col = colB0 + wn * (BN / 4) + ni * 16 + l16;
      const float bv = bias[col];
#pragma unroll
      for (int r = 0; r < 4; ++r) {
        const float v = acc[mi][ni][r] + bv;
        const int R = row0 + r;
        if constexpr (EPI == 0) {
          const int b = R >> 11, t = R & 2047;
          const int which = col >> 10, c = col & 1023;
          const int h = c >> 6, dd = c & 63;
          const size_t bh = (size_t)(b * 16 + h);
          if (which == 0)
            qws[(bh * 2048 + t) * 64 + dd] = f2bf(v * 0.125f);  // Q, scale folded
          else if (which == 1)
            kws[(bh * 2048 + t) * 64 + dd] = f2bf(v);           // K [bh][t][d]
          else
            vws[(bh * 64 + dd) * 2048 + t] = f2h(v);            // V^T f16 [bh][d][t]
        } else {
          out[(size_t)R * N + col] = v;
        }
      }
    }
  }
}

// ---------------------------------------------------------------------------
// MFMA flash attention (unchanged). Grid (64 bh, 16 qtiles), block 256.
// ---------------------------------------------------------------------------
__global__ __launch_bounds__(256, 2)
void attn_mfma_kernel(const unsigned short* __restrict__ qws,
                      const unsigned short* __restrict__ kws,
                      const unsigned short* __restrict__ vws,
                      unsigned short* __restrict__ yws) {
  constexpr int T = 2048, D = 64;
  __shared__ __align__(16) unsigned short Ks[128 * 72];
  __shared__ __align__(16) unsigned short Vs[64 * 136];
  const int tid = threadIdx.x;
  const int wid = tid >> 6, lane = tid & 63;
  const int hf = lane >> 5, l32 = lane & 31;
  const int bh = blockIdx.x;
  const int qt = 15 - (int)blockIdx.y;
  const int qbase = qt * 128;
  const unsigned short* Qp = qws + (size_t)bh * T * D;
  const unsigned short* Kp = kws + (size_t)bh * T * D;
  const unsigned short* Vp = vws + (size_t)bh * D * T;

  const int q = qbase + wid * 32 + l32;
  short8 qf[4];
#pragma unroll
  for (int s = 0; s < 4; ++s)
    qf[s] = *(const short8*)(Qp + (size_t)q * D + s * 16 + hf * 8);

  floatx16 Oacc[2];
#pragma unroll
  for (int mt2 = 0; mt2 < 2; ++mt2)
#pragma unroll
    for (int i = 0; i < 16; ++i) Oacc[mt2][i] = 0.f;
  float mrun = -1e30f, lrun = 0.f;

  for (int kt = 0; kt <= qt; ++kt) {
    const int kb = kt * 128;
    __syncthreads();
#pragma unroll
    for (int it = 0; it < 4; ++it) {
      const int e = it * 256 + tid;
      {
        const int row = e >> 3, c = (e & 7) * 8;
        *(short8*)&Ks[row * 72 + c] =
            *(const short8*)(Kp + (size_t)(kb + row) * D + c);
      }
      {
        const int row = e >> 4, c = (e & 15) * 8;
        *(short8*)&Vs[row * 136 + c] =
            *(const short8*)(Vp + (size_t)row * T + kb + c);
      }
    }
    __syncthreads();

    const bool diag = (kt == qt);
    const int mtmax = diag ? (wid + 1) : 4;

    floatx16 S[4];
#pragma unroll
    for (int mt = 0; mt < 4; ++mt)
      if (mt < mtmax)
#pragma unroll
        for (int i = 0; i < 16; ++i) S[mt][i] = 0.f;

#pragma unroll
    for (int s = 0; s < 4; ++s) {
#pragma unroll
      for (int mt = 0; mt < 4; ++mt)
        if (mt < mtmax) {
          const short8 kf =
              *(const short8*)&Ks[(mt * 32 + l32) * 72 + s * 16 + hf * 8];
          S[mt] = __builtin_amdgcn_mfma_f32_32x32x16_bf16(kf, qf[s], S[mt], 0, 0, 0);
        }
    }

    if (diag) {
#pragma unroll
      for (int mt = 0; mt < 4; ++mt)
        if (mt == wid) {
#pragma unroll
          for (int r = 0; r < 16; ++r) {
            const int intra = (r & 3) + 8 * (r >> 2) + 4 * hf;
            if (intra > l32) S[mt][r] = -1e30f;
          }
        }
    }

    float tmax = -1e30f;
#pragma unroll
    for (int mt = 0; mt < 4; ++mt)
      if (mt < mtmax)
#pragma unroll
        for (int r = 0; r < 16; ++r) tmax = fmaxf(tmax, S[mt][r]);
    tmax = fmaxf(tmax, __shfl_xor(tmax, 32, 64));
    const float mn = fmaxf(mrun, tmax);
    const float alpha = __expf(mrun - mn);
    mrun = mn;

    float tsum = 0.f;
    uint32_t pk[4][8];
#pragma unroll
    for (int mt = 0; mt < 4; ++mt)
      if (mt < mtmax)
#pragma unroll
        for (int t = 0; t < 8; ++t) {
          const float pa = __expf(S[mt][2 * t] - mn);
          const float pb = __expf(S[mt][2 * t + 1] - mn);
          tsum += pa + pb;
          union { fp16x2 h; uint32_t u; } cv;
          cv.h = __builtin_amdgcn_cvt_pkrtz(pa, pb);
          pk[mt][t] = cv.u;
        }
    tsum += __shfl_xor(tsum, 32, 64);
    lrun = lrun * alpha + tsum;
#pragma unroll
    for (int mt2 = 0; mt2 < 2; ++mt2)
#pragma unroll
      for (int i = 0; i < 16; ++i) Oacc[mt2][i] *= alpha;

    const int smax = 2 * mtmax;
#pragma unroll
    for (int s = 0; s < 8; ++s)
      if (s < smax) {
        const int mt = s >> 1;
        const int bo = 4 * (s & 1);
        const uint32_t own0 = hf ? pk[mt][bo + 2] : pk[mt][bo];
        const uint32_t own1 = hf ? pk[mt][bo + 3] : pk[mt][bo + 1];
        const uint32_t sendA = hf ? pk[mt][bo] : pk[mt][bo + 2];
        const uint32_t sendB = hf ? pk[mt][bo + 1] : pk[mt][bo + 3];
        const uint32_t recvA = (uint32_t)__shfl_xor((int)sendA, 32, 64);
        const uint32_t recvB = (uint32_t)__shfl_xor((int)sendB, 32, 64);
        union { uint32_t u[4]; half8 h; } bb;
        bb.u[0] = hf ? recvA : own0;
        bb.u[1] = hf ? recvB : own1;
        bb.u[2] = hf ? own0 : recvA;
        bb.u[3] = hf ? own1 : recvB;
#pragma unroll
        for (int mt2 = 0; mt2 < 2; ++mt2) {
          const half8 vf =
              *(const half8*)&Vs[(mt2 * 32 + l32) * 136 + s * 16 + hf * 8];
          Oacc[mt2] = __builtin_amdgcn_mfma_f32_32x32x16_f16(vf, bb.h, Oacc[mt2], 0, 0, 0);
        }
      }
  }

  const float invl = 1.0f / lrun;
  const int b_ = bh >> 4, h_ = bh & 15;
  unsigned short* yrow = yws + ((size_t)(b_ * 2048 + q)) * 1024 + h_ * 64;
#pragma unroll
  for (int mt2 = 0; mt2 < 2; ++mt2)
#pragma unroll
    for (int t = 0; t < 8; ++t) {
      const int d0 = mt2 * 32 + 2 * (t & 1) + 8 * (t >> 1) + 4 * hf;
      const uint32_t ua = f2bf(Oacc[mt2][2 * t] * invl);
      const uint32_t ub = f2bf(Oacc[mt2][2 * t + 1] * invl);
      *(uint32_t*)&yrow[d0] = ua | (ub << 16);
    }
}

// ---------------------------------------------------------------------------
extern "C" void kernel_launch(void* const* d_in, const int* in_sizes, int n_in,
                              void* d_out, int out_size, void* d_ws, size_t ws_size,
                              hipStream_t stream) {
  (void)in_sizes; (void)n_in; (void)out_size;
  const float* x = (const float*)d_in[0];
  const float* attn_w = (const float*)d_in[1];
  const float* attn_b = (const float*)d_in[2];
  const float* proj_w = (const float*)d_in[3];
  const float* proj_b = (const float*)d_in[4];
  float* out = (float*)d_out;

  const size_t NQ = 8388608;  // 4*16*2048*64 == 8192*1024
  unsigned short* qws = (unsigned short*)d_ws;
  unsigned short* kws = qws + NQ;
  unsigned short* vws = kws + NQ;
  unsigned short* yws = vws + NQ;
  unsigned short* xb  = yws + NQ;
  unsigned short* wta = xb + NQ;               // 3072*1024
  unsigned short* wtp = wta + 3072 * 1024;     // 1024*1024
  if (ws_size < (5 * NQ + 4 * 1024 * 1024) * sizeof(unsigned short)) return;

  cvt_x_kernel<<<dim3(8192), dim3(256), 0, stream>>>(x, xb);
  transpose_w_kernel<<<dim3(48, 16), dim3(256), 0, stream>>>(attn_w, wta, 1024, 3072);
  transpose_w_kernel<<<dim3(16, 16), dim3(256), 0, stream>>>(proj_w, wtp, 1024, 1024);

  // QKV: M=8192, N=3072 (BN=256) -> 32x12 = 384 blocks (384 % 8 == 0).
  gemm256_kernel<0, 256><<<dim3(384), dim3(512), 0, stream>>>(
      xb, wta, attn_b, 8192, 3072, 1024, 12, qws, kws, vws, nullptr);
  attn_mfma_kernel<<<dim3(64, 16), dim3(256), 0, stream>>>(qws, kws, vws, yws);
  // Proj: M=8192, N=1024 (BN=128) -> 32x8 = 256 blocks: one full round on 256 CUs.
  gemm256_kernel<1, 128><<<dim3(256), dim3(512), 0, stream>>>(
      yws, wtp, proj_b, 8192, 1024, 1024, 8, nullptr, nullptr, nullptr, out);
}